// Round 1
// baseline (654.270 us; speedup 1.0000x reference)
//
#include <hip/hip_runtime.h>

// out[N,32] = scatter_add over edges e: values[e] * x[cols[e], :]  into row rows[e]
// indices: d_in[0] = int[2*NNZ]  (rows = idx[0:NNZ], cols = idx[NNZ:2*NNZ])
// values:  d_in[1] = float[NNZ]
// x:       d_in[2] = float[N*32]
// out:     float[N*32]

#define D 32

__global__ __launch_bounds__(256) void spmm_scatter_kernel(
    const int* __restrict__ idx,
    const float* __restrict__ vals,
    const float* __restrict__ x,
    float* __restrict__ out,
    int nnz)
{
    int t = blockIdx.x * blockDim.x + threadIdx.x;
    int e = t >> 3;          // 8 threads per edge
    int q = t & 7;           // each handles 4 consecutive columns
    if (e >= nnz) return;

    int r = idx[e];          // row (scatter target)
    int c = idx[nnz + e];    // col (gather source)
    float v = vals[e];

    const float4 xv = reinterpret_cast<const float4*>(x)[(size_t)c * (D / 4) + q];
    float* o = out + (size_t)r * D + q * 4;
    atomicAdd(o + 0, v * xv.x);
    atomicAdd(o + 1, v * xv.y);
    atomicAdd(o + 2, v * xv.z);
    atomicAdd(o + 3, v * xv.w);
}

extern "C" void kernel_launch(void* const* d_in, const int* in_sizes, int n_in,
                              void* d_out, int out_size, void* d_ws, size_t ws_size,
                              hipStream_t stream)
{
    const int* idx   = (const int*)d_in[0];
    const float* val = (const float*)d_in[1];
    const float* x   = (const float*)d_in[2];
    float* out       = (float*)d_out;

    const int nnz = in_sizes[1];          // values element count = NNZ

    // Must zero the accumulator every call (harness poisons once, never re-poisons).
    hipMemsetAsync(d_out, 0, (size_t)out_size * sizeof(float), stream);

    const int threads = 256;
    const long long total = (long long)nnz * 8;
    const int blocks = (int)((total + threads - 1) / threads);
    spmm_scatter_kernel<<<blocks, threads, 0, stream>>>(idx, val, x, out, nnz);
}

// Round 2
// 246.487 us; speedup vs baseline: 2.6544x; 2.6544x over previous
//
#include <hip/hip_runtime.h>

// out[N,32] = scatter_add over edges e: values[e] * x[cols[e], :] into row rows[e]
// Strategy: build CSR on-device (histogram -> scan -> scatter), then gather-SpMM
// with register accumulation and zero output atomics.
//
// indices: d_in[0] = int[2*NNZ]  (rows = idx[0:NNZ], cols = idx[NNZ:2*NNZ])
// values:  d_in[1] = float[NNZ]
// x:       d_in[2] = float[N*32]
// out:     float[N*32]

#define D 32
#define SCAN_CHUNK 1024

// ---------- k1: histogram of row indices ----------
__global__ __launch_bounds__(256) void hist_kernel(
    const int* __restrict__ idx, int* __restrict__ cnt, int nnz)
{
    int e = blockIdx.x * blockDim.x + threadIdx.x;
    if (e < nnz) atomicAdd(&cnt[idx[e]], 1);
}

// ---------- k2a: per-chunk exclusive scan (Hillis-Steele in LDS) ----------
__global__ __launch_bounds__(SCAN_CHUNK) void scan_chunk_kernel(
    const int* __restrict__ cnt, int* __restrict__ row_start,
    int* __restrict__ blk_sums, int n_scan /* = N+1 */, int N)
{
    __shared__ int sm[SCAN_CHUNK];
    int i = blockIdx.x * SCAN_CHUNK + threadIdx.x;
    int v = (i < N) ? cnt[i] : 0;   // element N (virtual) is 0
    sm[threadIdx.x] = v;
    __syncthreads();
    for (int off = 1; off < SCAN_CHUNK; off <<= 1) {
        int t = sm[threadIdx.x];
        int u = (threadIdx.x >= off) ? sm[threadIdx.x - off] : 0;
        __syncthreads();
        sm[threadIdx.x] = t + u;
        __syncthreads();
    }
    if (i < n_scan) row_start[i] = sm[threadIdx.x] - v;  // exclusive
    if (threadIdx.x == SCAN_CHUNK - 1) blk_sums[blockIdx.x] = sm[SCAN_CHUNK - 1];
}

// ---------- k2b: scan the chunk totals (single block) ----------
__global__ __launch_bounds__(SCAN_CHUNK) void scan_blksums_kernel(
    int* __restrict__ blk_sums, int nb)
{
    __shared__ int sm[SCAN_CHUNK];
    int v = (threadIdx.x < nb) ? blk_sums[threadIdx.x] : 0;
    sm[threadIdx.x] = v;
    __syncthreads();
    for (int off = 1; off < SCAN_CHUNK; off <<= 1) {
        int t = sm[threadIdx.x];
        int u = (threadIdx.x >= off) ? sm[threadIdx.x - off] : 0;
        __syncthreads();
        sm[threadIdx.x] = t + u;
        __syncthreads();
    }
    if (threadIdx.x < nb) blk_sums[threadIdx.x] = sm[threadIdx.x] - v; // exclusive
}

// ---------- k2c: add chunk offsets; init cursor ----------
__global__ __launch_bounds__(SCAN_CHUNK) void add_offsets_kernel(
    int* __restrict__ row_start, int* __restrict__ cursor,
    const int* __restrict__ blk_sums, int n_scan, int N)
{
    int i = blockIdx.x * SCAN_CHUNK + threadIdx.x;
    if (i < n_scan) {
        int rs = row_start[i] + blk_sums[blockIdx.x];
        row_start[i] = rs;
        if (i < N) cursor[i] = rs;
    }
}

// ---------- k3: scatter edges into CSR slots ----------
__global__ __launch_bounds__(256) void scatter_kernel(
    const int* __restrict__ idx, const float* __restrict__ vals,
    int* __restrict__ cursor, int2* __restrict__ pairs, int nnz)
{
    int e = blockIdx.x * blockDim.x + threadIdx.x;
    if (e >= nnz) return;
    int r = idx[e];
    int c = idx[nnz + e];
    float v = vals[e];
    int pos = atomicAdd(&cursor[r], 1);
    pairs[pos] = make_int2(c, __float_as_int(v));
}

// ---------- k4: CSR SpMM, 8 threads/row, register accumulation ----------
__global__ __launch_bounds__(256) void spmm_csr_kernel(
    const int* __restrict__ row_start, const int2* __restrict__ pairs,
    const float* __restrict__ x, float* __restrict__ out, int N)
{
    int t = blockIdx.x * blockDim.x + threadIdx.x;
    int r = t >> 3;          // 8 threads per row
    int q = t & 7;           // 4 consecutive columns each
    if (r >= N) return;
    int s = row_start[r];
    int e = row_start[r + 1];
    const float4* __restrict__ x4 = reinterpret_cast<const float4*>(x);
    float4 acc = make_float4(0.f, 0.f, 0.f, 0.f);
    for (int k = s; k < e; ++k) {
        int2 p = pairs[k];                       // broadcast within the 8-group
        float v = __int_as_float(p.y);
        float4 xv = x4[(size_t)p.x * (D / 4) + q];
        acc.x += v * xv.x;
        acc.y += v * xv.y;
        acc.z += v * xv.z;
        acc.w += v * xv.w;
    }
    reinterpret_cast<float4*>(out)[(size_t)r * (D / 4) + q] = acc;
}

// ---------- fallback (round-1): direct atomic scatter ----------
__global__ __launch_bounds__(256) void spmm_scatter_kernel(
    const int* __restrict__ idx, const float* __restrict__ vals,
    const float* __restrict__ x, float* __restrict__ out, int nnz)
{
    int t = blockIdx.x * blockDim.x + threadIdx.x;
    int e = t >> 3;
    int q = t & 7;
    if (e >= nnz) return;
    int r = idx[e];
    int c = idx[nnz + e];
    float v = vals[e];
    const float4 xv = reinterpret_cast<const float4*>(x)[(size_t)c * (D / 4) + q];
    float* o = out + (size_t)r * D + q * 4;
    atomicAdd(o + 0, v * xv.x);
    atomicAdd(o + 1, v * xv.y);
    atomicAdd(o + 2, v * xv.z);
    atomicAdd(o + 3, v * xv.w);
}

static inline size_t align256(size_t v) { return (v + 255) & ~(size_t)255; }

extern "C" void kernel_launch(void* const* d_in, const int* in_sizes, int n_in,
                              void* d_out, int out_size, void* d_ws, size_t ws_size,
                              hipStream_t stream)
{
    const int* idx   = (const int*)d_in[0];
    const float* val = (const float*)d_in[1];
    const float* x   = (const float*)d_in[2];
    float* out       = (float*)d_out;

    const int nnz = in_sizes[1];
    const int N   = out_size / D;

    // ---- workspace layout (256B-aligned regions) ----
    size_t off_row_start = 0;
    size_t off_cnt       = align256(off_row_start + (size_t)(N + 1) * 4);
    size_t off_cursor    = align256(off_cnt       + (size_t)N * 4);
    size_t off_blksums   = align256(off_cursor    + (size_t)N * 4);
    size_t off_pairs     = align256(off_blksums   + (size_t)SCAN_CHUNK * 4);
    size_t ws_needed     = off_pairs + (size_t)nnz * 8;

    const int n_scan = N + 1;
    const int nb = (n_scan + SCAN_CHUNK - 1) / SCAN_CHUNK;

    if (ws_size < ws_needed || nb > SCAN_CHUNK) {
        // fallback: direct atomic scatter (round-1 kernel)
        hipMemsetAsync(d_out, 0, (size_t)out_size * sizeof(float), stream);
        const long long total = (long long)nnz * 8;
        const int blocks = (int)((total + 255) / 256);
        spmm_scatter_kernel<<<blocks, 256, 0, stream>>>(idx, val, x, out, nnz);
        return;
    }

    char* ws = (char*)d_ws;
    int*  row_start = (int*)(ws + off_row_start);
    int*  cnt       = (int*)(ws + off_cnt);
    int*  cursor    = (int*)(ws + off_cursor);
    int*  blk_sums  = (int*)(ws + off_blksums);
    int2* pairs     = (int2*)(ws + off_pairs);

    // k0: zero the histogram
    hipMemsetAsync(cnt, 0, (size_t)N * 4, stream);

    // k1: histogram rows
    hist_kernel<<<(nnz + 255) / 256, 256, 0, stream>>>(idx, cnt, nnz);

    // k2: exclusive scan -> row_start[N+1], cursor init
    scan_chunk_kernel<<<nb, SCAN_CHUNK, 0, stream>>>(cnt, row_start, blk_sums, n_scan, N);
    scan_blksums_kernel<<<1, SCAN_CHUNK, 0, stream>>>(blk_sums, nb);
    add_offsets_kernel<<<nb, SCAN_CHUNK, 0, stream>>>(row_start, cursor, blk_sums, n_scan, N);

    // k3: scatter (col, val) pairs into CSR order
    scatter_kernel<<<(nnz + 255) / 256, 256, 0, stream>>>(idx, val, cursor, pairs, nnz);

    // k4: gather SpMM, no output atomics, writes every output element
    const long long t4 = (long long)N * 8;
    spmm_csr_kernel<<<(int)((t4 + 255) / 256), 256, 0, stream>>>(row_start, pairs, x, out, N);
}